// Round 5
// baseline (1361.297 us; speedup 1.0000x reference)
//
#include <hip/hip_runtime.h>
#include <hip/hip_bf16.h>

constexpr int Kk = 27;
constexpr int Mm = 131072;            // 2^17
constexpr int Nn = 524288;            // 2^19
constexpr int Cc = 64;
constexpr float BN_EPS = 1e-5f;
constexpr int Ee = Kk * Mm;           // 3538944 entries
constexpr int NBUCKET = 2048;         // bucket = n >> 8  (256 output rows each)
constexpr int ACC_PAD = 65;           // f32 accumulator row stride (65 ≡ 1 mod 32)
constexpr int LCAP = 2048;            // per-half-bucket entry cap (mean 865, +40σ)
constexpr int MAXT = 160;             // max MFMA tiles per half-bucket

typedef __attribute__((ext_vector_type(8))) short bf16x8;
typedef __attribute__((ext_vector_type(4))) float f32x4;
typedef __attribute__((ext_vector_type(8))) unsigned short ushort8v;

// ---------------- ws layout ----------------
// 0      : stats (128 f32)            512: ss (128 f32)
// 1024   : Wf   (27*4096 ushort)      -> 222208
// 222208 : gh   (2048 u32 histogram)  -> 230400
// 230400 : seg_start (2052 u32)       -> 238608
// 238608 : cursor (2048 u32)          -> 246800
// 246800 : seg  (Ee u32 entries)      -> 14402576 (pad 14402688)
// 14402688: outb (N*64 bf16)          -> 81511552
constexpr size_t WF_OFF      = 1024;
constexpr size_t GH_OFF      = 222208;
constexpr size_t SEGSTART_OFF= 230400;
constexpr size_t CURSOR_OFF  = 238608;
constexpr size_t SEG_OFF     = 246800;
constexpr size_t OUTB_OFF    = 14402688;
constexpr size_t WS_NEW      = OUTB_OFF + (size_t)Nn * Cc * 2;   // 81511552

static __device__ __forceinline__ unsigned short f2bf(float f) {
    __hip_bfloat16 h = __float2bfloat16(f);
    return *reinterpret_cast<unsigned short*>(&h);
}
static __device__ __forceinline__ float bf2f(unsigned short u) {
    union { unsigned int i; float f; } v; v.i = ((unsigned int)u) << 16; return v.f;
}
static __device__ __forceinline__ unsigned int pk2(float a, float b) {
    return (unsigned int)f2bf(a) | ((unsigned int)f2bf(b) << 16);
}

// ---------------- W fragment convert (round-4 layout, verified) ----------------
// Wf[((k*8 + ct*2 + kk)*64 + lane)*8 + j] = bf16( W[k][kk*32+(lane>>4)*8+j][ct*16+(lane&15)] )
__global__ __launch_bounds__(256) void convert_w_kernel(
    const float* __restrict__ W, unsigned short* __restrict__ Wf)
{
    const int t = blockIdx.x * blockDim.x + threadIdx.x;
    if (t >= Kk * 4096) return;
    const int j    = t & 7;
    const int lane = (t >> 3) & 63;
    const int kk   = (t >> 9) & 1;
    const int ct   = (t >> 10) & 3;
    const int k    = t >> 12;
    const int cin  = kk * 32 + ((lane >> 4) & 3) * 8 + j;
    const int cout = ct * 16 + (lane & 15);
    Wf[t] = f2bf(W[(size_t)k * 4096 + cin * 64 + cout]);
}

// ---------------- inverted-index build ----------------
constexpr int IDX_BLOCKS = 256;
constexpr int CHUNK = Ee / IDX_BLOCKS;        // 13824 = 54*256

__global__ __launch_bounds__(256) void hist_kernel(
    const int* __restrict__ out_idx, unsigned int* __restrict__ gh)
{
    __shared__ unsigned int h[NBUCKET];
    const int tid = threadIdx.x;
#pragma unroll
    for (int j = 0; j < NBUCKET / 256; ++j) h[tid + j * 256] = 0;
    __syncthreads();
    const int p0 = blockIdx.x * CHUNK;
    for (int it = 0; it < CHUNK / 256; ++it) {
        const int n = out_idx[p0 + it * 256 + tid];
        atomicAdd(&h[n >> 8], 1u);
    }
    __syncthreads();
#pragma unroll
    for (int j = 0; j < NBUCKET / 256; ++j) {
        const int idx = tid + j * 256;
        if (h[idx]) atomicAdd(&gh[idx], h[idx]);
    }
}

__global__ __launch_bounds__(256) void scan_kernel(
    const unsigned int* __restrict__ gh, unsigned int* __restrict__ seg_start,
    unsigned int* __restrict__ cursor)
{
    const int t = threadIdx.x;
    unsigned int loc[8];
    unsigned int mysum = 0;
#pragma unroll
    for (int j = 0; j < 8; ++j) { loc[j] = gh[t * 8 + j]; mysum += loc[j]; }
    __shared__ unsigned int s[256];
    s[t] = mysum;
    __syncthreads();
    // Hillis-Steele inclusive scan
    for (int off = 1; off < 256; off <<= 1) {
        unsigned int v = (t >= off) ? s[t - off] : 0u;
        __syncthreads();
        s[t] += v;
        __syncthreads();
    }
    unsigned int run = s[t] - mysum;   // exclusive
#pragma unroll
    for (int j = 0; j < 8; ++j) {
        seg_start[t * 8 + j] = run;
        cursor[t * 8 + j]    = run;
        run += loc[j];
    }
    if (t == 255) seg_start[2048] = run;   // == Ee
}

// entry = local(8) | k(5)<<8 | in_row(19)<<13
__global__ __launch_bounds__(256) void place_kernel(
    const int* __restrict__ out_idx, const int* __restrict__ in_idx,
    unsigned int* __restrict__ cursor, unsigned int* __restrict__ seg)
{
    __shared__ unsigned int h[NBUCKET];
    __shared__ unsigned int base[NBUCKET];
    __shared__ unsigned int lcur[NBUCKET];
    const int tid = threadIdx.x;
#pragma unroll
    for (int j = 0; j < NBUCKET / 256; ++j) { h[tid + j * 256] = 0; lcur[tid + j * 256] = 0; }
    __syncthreads();
    const int p0 = blockIdx.x * CHUNK;
    for (int it = 0; it < CHUNK / 256; ++it) {
        const int n = out_idx[p0 + it * 256 + tid];
        atomicAdd(&h[n >> 8], 1u);
    }
    __syncthreads();
#pragma unroll
    for (int j = 0; j < NBUCKET / 256; ++j) {
        const int idx = tid + j * 256;
        base[idx] = h[idx] ? atomicAdd(&cursor[idx], h[idx]) : 0u;
    }
    __syncthreads();
    for (int it = 0; it < CHUNK / 256; ++it) {
        const int p = p0 + it * 256 + tid;
        const int n = out_idx[p];
        const int ir = in_idx[p];
        const int k = p >> 17;
        const unsigned int e = (unsigned int)(n & 255) | ((unsigned int)k << 8)
                             | ((unsigned int)ir << 13);
        const int b = n >> 8;
        const unsigned int pos = base[b] + atomicAdd(&lcur[b], 1u);
        seg[pos] = e;
    }
}

// ---------------- bucketed gather-MFMA-accumulate (no global atomics) ----------------
// One block per half-bucket (128 output rows). Entries sorted by k in LDS;
// per k-group 16-entry MFMA tiles (swapped operands, round-4 verified layout);
// f32 LDS accumulator (stride 65); final single write of each output row + BN stats.
__global__ __launch_bounds__(256) void bucket_main_kernel(
    const float* __restrict__ x, const unsigned short* __restrict__ Wf,
    const unsigned int* __restrict__ seg_start, const unsigned int* __restrict__ seg,
    unsigned short* __restrict__ outb, float* __restrict__ stats)
{
    __shared__ unsigned int raw[LCAP];
    __shared__ unsigned int sortedE[LCAP];
    __shared__ float accf[128 * ACC_PAD];      // 33.3 KB
    __shared__ unsigned int khist[32];
    __shared__ unsigned int kcur[32];
    __shared__ unsigned int tinfo[MAXT];       // base(12) | valid(5)<<12 | k(5)<<17
    __shared__ unsigned int nloc_s, ntiles_s;

    const int tid  = threadIdx.x;
    const int lane = tid & 63;
    const int wv   = tid >> 6;
    const int lrow = lane & 15;
    const int lgrp = lane >> 4;

    const int bucket = blockIdx.x >> 1;
    const int half   = blockIdx.x & 1;
    const unsigned int s0 = seg_start[bucket];
    const unsigned int cnt = seg_start[bucket + 1] - s0;

    if (tid == 0) { nloc_s = 0; ntiles_s = 0; }
    if (tid < 32) khist[tid] = 0;
    for (int j = tid; j < 128 * ACC_PAD; j += 256) accf[j] = 0.f;
    __syncthreads();

    // load + filter this half's entries
    for (unsigned int i = tid; i < cnt; i += 256) {
        const unsigned int e = seg[s0 + i];
        if ((int)((e >> 7) & 1u) == half) {
            const unsigned int idx = atomicAdd(&nloc_s, 1u);
            if (idx < LCAP) raw[idx] = e;
        }
    }
    __syncthreads();
    const unsigned int nloc = (nloc_s < LCAP) ? nloc_s : LCAP;

    // k-histogram
    for (unsigned int i = tid; i < nloc; i += 256)
        atomicAdd(&khist[(raw[i] >> 8) & 31u], 1u);
    __syncthreads();

    // serial: k offsets, cursors, tile table
    if (tid == 0) {
        unsigned int off = 0, nt = 0;
        for (int k = 0; k < Kk; ++k) {
            const unsigned int g = khist[k];
            kcur[k] = off;
            unsigned int t_in_k = 0;
            while (t_in_k * 16 < g && nt < MAXT) {
                const unsigned int valid = min(16u, g - t_in_k * 16);
                tinfo[nt++] = (off + t_in_k * 16) | (valid << 12) | ((unsigned int)k << 17);
                ++t_in_k;
            }
            off += g;
        }
        ntiles_s = nt;
    }
    __syncthreads();

    // place sorted by k
    for (unsigned int i = tid; i < nloc; i += 256) {
        const unsigned int e = raw[i];
        const unsigned int pos = atomicAdd(&kcur[(e >> 8) & 31u], 1u);
        sortedE[pos] = e;
    }
    __syncthreads();
    const unsigned int ntiles = ntiles_s;

    // MFMA tiles, round-robin over waves
    for (unsigned int t = wv; t < ntiles; t += 4) {
        const unsigned int ti = tinfo[t];
        const unsigned int ebase = ti & 0xFFFu;
        const unsigned int valid = (ti >> 12) & 31u;
        const unsigned int k     = ti >> 17;

        // W fragments for this k (L1-resident reload)
        const unsigned short* Wk = Wf + (size_t)k * 4096;
        bf16x8 B[4][2];
#pragma unroll
        for (int ct = 0; ct < 4; ++ct)
#pragma unroll
            for (int kk = 0; kk < 2; ++kk)
                B[ct][kk] = *reinterpret_cast<const bf16x8*>(Wk + ((ct * 2 + kk) * 64 + lane) * 8);

        const bool vl = (unsigned int)lrow < valid;
        const unsigned int e = sortedE[ebase + (vl ? lrow : 0)];
        const unsigned int row  = e & 127u;
        const unsigned int in_r = e >> 13;

        bf16x8 X0 = (bf16x8)(short)0, X1 = (bf16x8)(short)0;
        if (vl) {
            const float* xr = x + (size_t)in_r * Cc + lgrp * 8;
            const float4 a0 = *reinterpret_cast<const float4*>(xr);
            const float4 a1 = *reinterpret_cast<const float4*>(xr + 4);
            const float4 b0 = *reinterpret_cast<const float4*>(xr + 32);
            const float4 b1 = *reinterpret_cast<const float4*>(xr + 36);
            X0[0]=(short)f2bf(a0.x); X0[1]=(short)f2bf(a0.y); X0[2]=(short)f2bf(a0.z); X0[3]=(short)f2bf(a0.w);
            X0[4]=(short)f2bf(a1.x); X0[5]=(short)f2bf(a1.y); X0[6]=(short)f2bf(a1.z); X0[7]=(short)f2bf(a1.w);
            X1[0]=(short)f2bf(b0.x); X1[1]=(short)f2bf(b0.y); X1[2]=(short)f2bf(b0.z); X1[3]=(short)f2bf(b0.w);
            X1[4]=(short)f2bf(b1.x); X1[5]=(short)f2bf(b1.y); X1[6]=(short)f2bf(b1.z); X1[7]=(short)f2bf(b1.w);
        }

        f32x4 acc[4];
#pragma unroll
        for (int ct = 0; ct < 4; ++ct) {
            acc[ct] = __builtin_amdgcn_mfma_f32_16x16x32_bf16(
                B[ct][0], X0, (f32x4){0.f, 0.f, 0.f, 0.f}, 0, 0, 0);
            acc[ct] = __builtin_amdgcn_mfma_f32_16x16x32_bf16(
                B[ct][1], X1, acc[ct], 0, 0, 0);
        }
        // lane (lrow,lgrp) holds ch ct*16+lgrp*4+j of entry lrow's output row
        if (vl) {
#pragma unroll
            for (int ct = 0; ct < 4; ++ct)
#pragma unroll
                for (int j = 0; j < 4; ++j)
                    atomicAdd(&accf[row * ACC_PAD + ct * 16 + lgrp * 4 + j], acc[ct][j]);
        }
    }
    __syncthreads();

    // BN partial stats: thread t -> ch = t&63, row-group t>>6 (32 rows each)
    {
        const int ch = tid & 63;
        const int rg = tid >> 6;
        float s = 0.f, q = 0.f;
        for (int r = rg * 32; r < rg * 32 + 32; ++r) {
            const float v = accf[r * ACC_PAD + ch];
            s += v;
            q = fmaf(v, v, q);
        }
        float* fs = reinterpret_cast<float*>(raw);   // reuse (512 f32)
        fs[rg * 64 + ch] = s;
        fs[256 + rg * 64 + ch] = q;
        __syncthreads();
        if (tid < 64) {
            const float ts = fs[tid] + fs[64 + tid] + fs[128 + tid] + fs[192 + tid];
            const float tq = fs[256 + tid] + fs[320 + tid] + fs[384 + tid] + fs[448 + tid];
            atomicAdd(stats + tid, ts);
            atomicAdd(stats + 64 + tid, tq);
        }
    }

    // write 128 rows (each exactly once): thread t -> row t>>1, ch half (t&1)*32
    {
        const int r  = tid >> 1;
        const int c0 = (tid & 1) * 32;
        const size_t nrow = (size_t)bucket * 256 + half * 128 + r;
        unsigned int pkv[16];
#pragma unroll
        for (int j = 0; j < 16; ++j)
            pkv[j] = pk2(accf[r * ACC_PAD + c0 + 2 * j], accf[r * ACC_PAD + c0 + 2 * j + 1]);
        uint4* dst = reinterpret_cast<uint4*>(outb + nrow * Cc + c0);
#pragma unroll
        for (int j = 0; j < 4; ++j)
            dst[j] = make_uint4(pkv[4 * j], pkv[4 * j + 1], pkv[4 * j + 2], pkv[4 * j + 3]);
    }
}

// ---------------- BN finalize + apply ----------------
__global__ void bn_finalize_kernel(const float* __restrict__ stats,
                                   const float* __restrict__ gamma,
                                   const float* __restrict__ beta,
                                   float* __restrict__ ss)
{
    const int c = threadIdx.x;
    const float inv_n = 1.f / (float)Nn;
    const float mean = stats[c] * inv_n;
    const float var  = stats[64 + c] * inv_n - mean * mean;
    const float scale = gamma[c] * rsqrtf(var + BN_EPS);
    ss[c]      = scale;
    ss[64 + c] = beta[c] - mean * scale;
}

__global__ __launch_bounds__(256) void bn_apply_bf16(
    const unsigned short* __restrict__ outb, const float* __restrict__ ss,
    float* __restrict__ out)
{
    const int tid = threadIdx.x;
    const int cg = (tid & 7) * 8;
    float sc[8], sh[8];
#pragma unroll
    for (int j = 0; j < 8; ++j) { sc[j] = ss[cg + j]; sh[j] = ss[64 + cg + j]; }
    const size_t total8 = (size_t)Nn * Cc / 8;
    const ushort8v* p = reinterpret_cast<const ushort8v*>(outb);
    float4* o4 = reinterpret_cast<float4*>(out);
    for (size_t i = (size_t)blockIdx.x * 256 + tid; i < total8;
         i += (size_t)gridDim.x * 256) {
        const ushort8v v = p[i];
        float4 lo, hi;
        lo.x = fmaxf(fmaf(bf2f(v[0]), sc[0], sh[0]), 0.f);
        lo.y = fmaxf(fmaf(bf2f(v[1]), sc[1], sh[1]), 0.f);
        lo.z = fmaxf(fmaf(bf2f(v[2]), sc[2], sh[2]), 0.f);
        lo.w = fmaxf(fmaf(bf2f(v[3]), sc[3], sh[3]), 0.f);
        hi.x = fmaxf(fmaf(bf2f(v[4]), sc[4], sh[4]), 0.f);
        hi.y = fmaxf(fmaf(bf2f(v[5]), sc[5], sh[5]), 0.f);
        hi.z = fmaxf(fmaf(bf2f(v[6]), sc[6], sh[6]), 0.f);
        hi.w = fmaxf(fmaf(bf2f(v[7]), sc[7], sh[7]), 0.f);
        o4[i * 2]     = lo;
        o4[i * 2 + 1] = hi;
    }
}

// ---------------- fp32 fallback (tiny-ws safety, round-1 path) ----------------
__global__ __launch_bounds__(256) void scatter_gemm_kernel(
    const float* __restrict__ x, const float* __restrict__ W,
    const int* __restrict__ in_idx, const int* __restrict__ out_idx,
    float* __restrict__ out)
{
    const int tid  = threadIdx.x;
    const int lane = tid & 63;
    const int w    = tid >> 6;
    const int k     = blockIdx.x / 1024;
    const int chunk = blockIdx.x % 1024;
    const int m0    = chunk * 128 + w * 32;

    const float* Wk = W + k * (Cc * Cc);
    float wcol[Cc];
#pragma unroll
    for (int i = 0; i < Cc; ++i) wcol[i] = Wk[i * Cc + lane];

    const int* inI  = in_idx  + (size_t)k * Mm + m0;
    const int* outI = out_idx + (size_t)k * Mm + m0;

    __shared__ float xs[4][32][Cc];
    for (int r = 0; r < 32; ++r)
        xs[w][r][lane] = x[(size_t)inI[r] * Cc + lane];
    for (int r = 0; r < 32; ++r) {
        const float* xr = &xs[w][r][0];
        float acc = 0.f;
#pragma unroll
        for (int i = 0; i < Cc; i += 4) {
            const float4 xv = *reinterpret_cast<const float4*>(xr + i);
            acc = fmaf(xv.x, wcol[i + 0], acc);
            acc = fmaf(xv.y, wcol[i + 1], acc);
            acc = fmaf(xv.z, wcol[i + 2], acc);
            acc = fmaf(xv.w, wcol[i + 3], acc);
        }
        atomicAdd(out + (size_t)outI[r] * Cc + lane, acc);
    }
}

__global__ __launch_bounds__(256) void bn_stats_f32(
    const float* __restrict__ out, float* __restrict__ stats)
{
    const int tid = threadIdx.x;
    const int c = tid & 63;
    const int g = tid >> 6;
    float s = 0.f, sq = 0.f;
    for (int r = blockIdx.x * 4 + g; r < Nn; r += gridDim.x * 4) {
        const float v = out[(size_t)r * Cc + c];
        s += v;
        sq = fmaf(v, v, sq);
    }
    __shared__ float lsum[4][64];
    __shared__ float lsq[4][64];
    lsum[g][c] = s;
    lsq[g][c]  = sq;
    __syncthreads();
    if (tid < 64) {
        atomicAdd(stats + c,      lsum[0][c] + lsum[1][c] + lsum[2][c] + lsum[3][c]);
        atomicAdd(stats + 64 + c, lsq[0][c] + lsq[1][c] + lsq[2][c] + lsq[3][c]);
    }
}

__global__ __launch_bounds__(256) void bn_apply_f32(
    float* __restrict__ out, const float* __restrict__ ss)
{
    const size_t total4 = (size_t)Nn * Cc / 4;
    const float4* ssc = reinterpret_cast<const float4*>(ss);
    float4* o4 = reinterpret_cast<float4*>(out);
    for (size_t i = (size_t)blockIdx.x * blockDim.x + threadIdx.x; i < total4;
         i += (size_t)gridDim.x * blockDim.x) {
        const int c4 = (int)(i & 15);
        const float4 sc = ssc[c4];
        const float4 sh = ssc[16 + c4];
        float4 v = o4[i];
        v.x = fmaxf(fmaf(v.x, sc.x, sh.x), 0.f);
        v.y = fmaxf(fmaf(v.y, sc.y, sh.y), 0.f);
        v.z = fmaxf(fmaf(v.z, sc.z, sh.z), 0.f);
        v.w = fmaxf(fmaf(v.w, sc.w, sh.w), 0.f);
        o4[i] = v;
    }
}

extern "C" void kernel_launch(void* const* d_in, const int* in_sizes, int n_in,
                              void* d_out, int out_size, void* d_ws, size_t ws_size,
                              hipStream_t stream) {
    const float* x      = (const float*)d_in[0];
    const float* W      = (const float*)d_in[1];
    const float* gamma  = (const float*)d_in[2];
    const float* beta   = (const float*)d_in[3];
    const int*   in_idx = (const int*)d_in[4];
    const int*   out_idx= (const int*)d_in[5];
    float* out   = (float*)d_out;
    char*  ws    = (char*)d_ws;
    float* stats = (float*)ws;
    float* ss    = stats + 128;

    hipMemsetAsync(d_ws, 0, 256 * sizeof(float), stream);

    if (ws_size >= WS_NEW) {
        unsigned short* Wf       = (unsigned short*)(ws + WF_OFF);
        unsigned int*   gh       = (unsigned int*)(ws + GH_OFF);
        unsigned int*   segstart = (unsigned int*)(ws + SEGSTART_OFF);
        unsigned int*   cursor   = (unsigned int*)(ws + CURSOR_OFF);
        unsigned int*   seg      = (unsigned int*)(ws + SEG_OFF);
        unsigned short* outb     = (unsigned short*)(ws + OUTB_OFF);

        hipMemsetAsync(gh, 0, NBUCKET * sizeof(unsigned int), stream);
        convert_w_kernel<<<(Kk * 4096 + 255) / 256, 256, 0, stream>>>(W, Wf);
        hist_kernel<<<IDX_BLOCKS, 256, 0, stream>>>(out_idx, gh);
        scan_kernel<<<1, 256, 0, stream>>>(gh, segstart, cursor);
        place_kernel<<<IDX_BLOCKS, 256, 0, stream>>>(out_idx, in_idx, cursor, seg);
        bucket_main_kernel<<<NBUCKET * 2, 256, 0, stream>>>(
            x, Wf, segstart, seg, outb, stats);
        bn_finalize_kernel<<<1, 64, 0, stream>>>(stats, gamma, beta, ss);
        bn_apply_bf16<<<2048, 256, 0, stream>>>(outb, ss, out);
    } else {
        hipMemsetAsync(d_out, 0, (size_t)Nn * Cc * sizeof(float), stream);
        scatter_gemm_kernel<<<Kk * 1024, 256, 0, stream>>>(x, W, in_idx, out_idx, out);
        bn_stats_f32<<<1024, 256, 0, stream>>>(out, stats);
        bn_finalize_kernel<<<1, 64, 0, stream>>>(stats, gamma, beta, ss);
        bn_apply_f32<<<4096, 256, 0, stream>>>(out, ss);
    }
}

// Round 6
// 451.840 us; speedup vs baseline: 3.0128x; 3.0128x over previous
//
#include <hip/hip_runtime.h>
#include <hip/hip_bf16.h>

constexpr int Kk = 27;
constexpr int Mm = 131072;
constexpr int Nn = 524288;
constexpr int Cc = 64;
constexpr float BN_EPS = 1e-5f;

typedef __attribute__((ext_vector_type(8))) short bf16x8;
typedef __attribute__((ext_vector_type(4))) float f32x4;
typedef __attribute__((ext_vector_type(8))) unsigned short ushort8v;

// ---------------- ws layout ----------------
// 0      : stats (128 f32)     512: ss (128 f32)
// 1024   : Wf (27*4096 ushort) -> 222208
// 222208 : outb (N*64 bf16)    -> 67331072
constexpr size_t WF_OFF   = 1024;
constexpr size_t OUTB_OFF = 222208;                       // 128B aligned
constexpr size_t ROWBUF_BYTES = (size_t)Nn * Cc * 2;      // 67108864
constexpr size_t WS_NEEDED = OUTB_OFF + ROWBUF_BYTES;     // 67331072

static __device__ __forceinline__ unsigned short f2bf(float f) {
    __hip_bfloat16 h = __float2bfloat16(f);
    return *reinterpret_cast<unsigned short*>(&h);
}
static __device__ __forceinline__ float bf2f(unsigned short u) {
    union { unsigned int i; float f; } v; v.i = ((unsigned int)u) << 16; return v.f;
}
static __device__ __forceinline__ unsigned int pk2(float a, float b) {
    return (unsigned int)f2bf(a) | ((unsigned int)f2bf(b) << 16);
}
static __device__ __forceinline__ void atomic_pk_bf16(unsigned short* p, unsigned int v) {
    asm volatile("global_atomic_pk_add_bf16 %0, %1, off"
                 :: "v"((unsigned long long)(uintptr_t)p), "v"(v) : "memory");
}

// Wf[((k*8 + ct*2 + kk)*64 + lane)*8 + j] = bf16( W[k][kk*32+(lane>>4)*8+j][ct*16+(lane&15)] )
__global__ __launch_bounds__(256) void convert_w_kernel(
    const float* __restrict__ W, unsigned short* __restrict__ Wf)
{
    const int t = blockIdx.x * blockDim.x + threadIdx.x;
    if (t >= Kk * 4096) return;
    const int j    = t & 7;
    const int lane = (t >> 3) & 63;
    const int kk   = (t >> 9) & 1;
    const int ct   = (t >> 10) & 3;
    const int k    = t >> 12;
    const int cin  = kk * 32 + ((lane >> 4) & 3) * 8 + j;
    const int cout = ct * 16 + (lane & 15);
    Wf[t] = f2bf(W[(size_t)k * 4096 + cin * 64 + cout]);
}

// ---------------- swapped-operand MFMA + full-line pk-bf16 scatter ----------------
// (round-4 verified structure; direct f32 gather with inline bf16 convert)
constexpr int RPB2 = 256;
constexpr int BPK2 = Mm / RPB2;   // 512
constexpr int TPAD = 68;          // LDS bounce-tile row stride (ushorts)

__global__ __launch_bounds__(256) void scatter_pk_kernel(
    const float* __restrict__ x, const unsigned short* __restrict__ Wf,
    const int* __restrict__ in_idx, const int* __restrict__ out_idx,
    unsigned short* __restrict__ outb)
{
    const int tid  = threadIdx.x;
    const int lane = tid & 63;
    const int w    = tid >> 6;
    const int k     = blockIdx.x / BPK2;
    const int chunk = blockIdx.x % BPK2;
    const int m0    = chunk * RPB2 + w * 64;

    const int lrow = lane & 15;
    const int lgrp = lane >> 4;
    const int hi   = lane >> 5;     // 0/1
    const int cpr  = lane & 31;     // channel-pair within row

    __shared__ unsigned short tile[4][2][16][TPAD];   // per-wave double-buffered

    const unsigned short* Wk = Wf + (size_t)k * 4096;
    bf16x8 B[4][2];
#pragma unroll
    for (int ct = 0; ct < 4; ++ct)
#pragma unroll
        for (int kk = 0; kk < 2; ++kk)
            B[ct][kk] = *reinterpret_cast<const bf16x8*>(Wk + ((ct * 2 + kk) * 64 + lane) * 8);

    const int* inI  = in_idx  + (size_t)k * Mm + m0;
    const int* outI = out_idx + (size_t)k * Mm + m0;

#pragma unroll
    for (int rt = 0; rt < 4; ++rt) {
        const int base = rt * 16;
        const int ridx = inI[base + lrow];

        // gather f32 row fragment, convert to bf16 inline
        const float* xr = x + (size_t)ridx * Cc + lgrp * 8;
        const float4 a0 = *reinterpret_cast<const float4*>(xr);
        const float4 a1 = *reinterpret_cast<const float4*>(xr + 4);
        const float4 b0 = *reinterpret_cast<const float4*>(xr + 32);
        const float4 b1 = *reinterpret_cast<const float4*>(xr + 36);
        bf16x8 X0, X1;
        X0[0]=(short)f2bf(a0.x); X0[1]=(short)f2bf(a0.y); X0[2]=(short)f2bf(a0.z); X0[3]=(short)f2bf(a0.w);
        X0[4]=(short)f2bf(a1.x); X0[5]=(short)f2bf(a1.y); X0[6]=(short)f2bf(a1.z); X0[7]=(short)f2bf(a1.w);
        X1[0]=(short)f2bf(b0.x); X1[1]=(short)f2bf(b0.y); X1[2]=(short)f2bf(b0.z); X1[3]=(short)f2bf(b0.w);
        X1[4]=(short)f2bf(b1.x); X1[5]=(short)f2bf(b1.y); X1[6]=(short)f2bf(b1.z); X1[7]=(short)f2bf(b1.w);

        const int oi = outI[base + lrow];

        f32x4 acc[4];
#pragma unroll
        for (int ct = 0; ct < 4; ++ct) {
            acc[ct] = __builtin_amdgcn_mfma_f32_16x16x32_bf16(
                B[ct][0], X0, (f32x4){0.f, 0.f, 0.f, 0.f}, 0, 0, 0);
            acc[ct] = __builtin_amdgcn_mfma_f32_16x16x32_bf16(
                B[ct][1], X1, acc[ct], 0, 0, 0);
        }

        // stage this wave's 16x64 bf16 result tile (wave-private, no barrier)
        const int buf = rt & 1;
#pragma unroll
        for (int ct = 0; ct < 4; ++ct) {
            uint2 pv;
            pv.x = pk2(acc[ct][0], acc[ct][1]);
            pv.y = pk2(acc[ct][2], acc[ct][3]);
            *reinterpret_cast<uint2*>(&tile[w][buf][lrow][ct * 16 + lgrp * 4]) = pv;
        }

        // row-major re-read: instruction j covers rows 2j,2j+1 fully
        const unsigned int* tdw = reinterpret_cast<const unsigned int*>(&tile[w][buf][0][0]);
#pragma unroll
        for (int j = 0; j < 8; ++j) {
            const int row = 2 * j + hi;
            const unsigned int v = tdw[row * (TPAD / 2) + cpr];
            const int roi = __shfl(oi, row, 64);
            atomic_pk_bf16(outb + (size_t)roi * Cc + cpr * 2, v);
        }
    }
}

// ---------------- BN on bf16 buffer ----------------
__global__ __launch_bounds__(256) void bn_stats_bf16(
    const unsigned short* __restrict__ outb, float* __restrict__ stats)
{
    const int tid = threadIdx.x;
    const int lane = tid & 63;
    const int w = tid >> 6;
    const size_t total8 = (size_t)Nn * Cc / 8;
    float s[8] = {0,0,0,0,0,0,0,0};
    float q[8] = {0,0,0,0,0,0,0,0};
    const ushort8v* p = reinterpret_cast<const ushort8v*>(outb);
    for (size_t i = (size_t)blockIdx.x * 256 + tid; i < total8;
         i += (size_t)gridDim.x * 256) {
        const ushort8v v = p[i];
#pragma unroll
        for (int j = 0; j < 8; ++j) {
            const float f = bf2f(v[j]);
            s[j] += f;
            q[j] = fmaf(f, f, q[j]);
        }
    }
#pragma unroll
    for (int off = 8; off < 64; off <<= 1) {
#pragma unroll
        for (int j = 0; j < 8; ++j) {
            s[j] += __shfl_xor(s[j], off, 64);
            q[j] += __shfl_xor(q[j], off, 64);
        }
    }
    __shared__ float ls[4][8][8];
    __shared__ float lq[4][8][8];
    if (lane < 8) {
#pragma unroll
        for (int j = 0; j < 8; ++j) { ls[w][lane][j] = s[j]; lq[w][lane][j] = q[j]; }
    }
    __syncthreads();
    if (tid < 64) {
        const int g = tid >> 3, j = tid & 7;
        const float ts = ls[0][g][j] + ls[1][g][j] + ls[2][g][j] + ls[3][g][j];
        const float tq = lq[0][g][j] + lq[1][g][j] + lq[2][g][j] + lq[3][g][j];
        atomicAdd(stats + tid, ts);
        atomicAdd(stats + 64 + tid, tq);
    }
}

__global__ void bn_finalize_kernel(const float* __restrict__ stats,
                                   const float* __restrict__ gamma,
                                   const float* __restrict__ beta,
                                   float* __restrict__ ss)
{
    const int c = threadIdx.x;
    const float inv_n = 1.f / (float)Nn;
    const float mean = stats[c] * inv_n;
    const float var  = stats[64 + c] * inv_n - mean * mean;
    const float scale = gamma[c] * rsqrtf(var + BN_EPS);
    ss[c]      = scale;
    ss[64 + c] = beta[c] - mean * scale;
}

__global__ __launch_bounds__(256) void bn_apply_bf16(
    const unsigned short* __restrict__ outb, const float* __restrict__ ss,
    float* __restrict__ out)
{
    const int tid = threadIdx.x;
    const int cg = (tid & 7) * 8;
    float sc[8], sh[8];
#pragma unroll
    for (int j = 0; j < 8; ++j) { sc[j] = ss[cg + j]; sh[j] = ss[64 + cg + j]; }
    const size_t total8 = (size_t)Nn * Cc / 8;
    const ushort8v* p = reinterpret_cast<const ushort8v*>(outb);
    float4* o4 = reinterpret_cast<float4*>(out);
    for (size_t i = (size_t)blockIdx.x * 256 + tid; i < total8;
         i += (size_t)gridDim.x * 256) {
        const ushort8v v = p[i];
        float4 lo, hi;
        lo.x = fmaxf(fmaf(bf2f(v[0]), sc[0], sh[0]), 0.f);
        lo.y = fmaxf(fmaf(bf2f(v[1]), sc[1], sh[1]), 0.f);
        lo.z = fmaxf(fmaf(bf2f(v[2]), sc[2], sh[2]), 0.f);
        lo.w = fmaxf(fmaf(bf2f(v[3]), sc[3], sh[3]), 0.f);
        hi.x = fmaxf(fmaf(bf2f(v[4]), sc[4], sh[4]), 0.f);
        hi.y = fmaxf(fmaf(bf2f(v[5]), sc[5], sh[5]), 0.f);
        hi.z = fmaxf(fmaf(bf2f(v[6]), sc[6], sh[6]), 0.f);
        hi.w = fmaxf(fmaf(bf2f(v[7]), sc[7], sh[7]), 0.f);
        o4[i * 2]     = lo;
        o4[i * 2 + 1] = hi;
    }
}

// ---------------- fp32 fallback (tiny-ws safety, round-1 path) ----------------
__global__ __launch_bounds__(256) void scatter_gemm_kernel(
    const float* __restrict__ x, const float* __restrict__ W,
    const int* __restrict__ in_idx, const int* __restrict__ out_idx,
    float* __restrict__ out)
{
    const int tid  = threadIdx.x;
    const int lane = tid & 63;
    const int w    = tid >> 6;
    const int k     = blockIdx.x / 1024;
    const int chunk = blockIdx.x % 1024;
    const int m0    = chunk * 128 + w * 32;

    const float* Wk = W + k * (Cc * Cc);
    float wcol[Cc];
#pragma unroll
    for (int i = 0; i < Cc; ++i) wcol[i] = Wk[i * Cc + lane];

    const int* inI  = in_idx  + (size_t)k * Mm + m0;
    const int* outI = out_idx + (size_t)k * Mm + m0;

    __shared__ float xs[4][32][Cc];
    for (int r = 0; r < 32; ++r)
        xs[w][r][lane] = x[(size_t)inI[r] * Cc + lane];
    for (int r = 0; r < 32; ++r) {
        const float* xr = &xs[w][r][0];
        float acc = 0.f;
#pragma unroll
        for (int i = 0; i < Cc; i += 4) {
            const float4 xv = *reinterpret_cast<const float4*>(xr + i);
            acc = fmaf(xv.x, wcol[i + 0], acc);
            acc = fmaf(xv.y, wcol[i + 1], acc);
            acc = fmaf(xv.z, wcol[i + 2], acc);
            acc = fmaf(xv.w, wcol[i + 3], acc);
        }
        atomicAdd(out + (size_t)outI[r] * Cc + lane, acc);
    }
}

__global__ __launch_bounds__(256) void bn_stats_f32(
    const float* __restrict__ out, float* __restrict__ stats)
{
    const int tid = threadIdx.x;
    const int c = tid & 63;
    const int g = tid >> 6;
    float s = 0.f, sq = 0.f;
    for (int r = blockIdx.x * 4 + g; r < Nn; r += gridDim.x * 4) {
        const float v = out[(size_t)r * Cc + c];
        s += v;
        sq = fmaf(v, v, sq);
    }
    __shared__ float lsum[4][64];
    __shared__ float lsq[4][64];
    lsum[g][c] = s;
    lsq[g][c]  = sq;
    __syncthreads();
    if (tid < 64) {
        atomicAdd(stats + c,      lsum[0][c] + lsum[1][c] + lsum[2][c] + lsum[3][c]);
        atomicAdd(stats + 64 + c, lsq[0][c] + lsq[1][c] + lsq[2][c] + lsq[3][c]);
    }
}

__global__ __launch_bounds__(256) void bn_apply_f32(
    float* __restrict__ out, const float* __restrict__ ss)
{
    const size_t total4 = (size_t)Nn * Cc / 4;
    const float4* ssc = reinterpret_cast<const float4*>(ss);
    float4* o4 = reinterpret_cast<float4*>(out);
    for (size_t i = (size_t)blockIdx.x * blockDim.x + threadIdx.x; i < total4;
         i += (size_t)gridDim.x * blockDim.x) {
        const int c4 = (int)(i & 15);
        const float4 sc = ssc[c4];
        const float4 sh = ssc[16 + c4];
        float4 v = o4[i];
        v.x = fmaxf(fmaf(v.x, sc.x, sh.x), 0.f);
        v.y = fmaxf(fmaf(v.y, sc.y, sh.y), 0.f);
        v.z = fmaxf(fmaf(v.z, sc.z, sh.z), 0.f);
        v.w = fmaxf(fmaf(v.w, sc.w, sh.w), 0.f);
        o4[i] = v;
    }
}

extern "C" void kernel_launch(void* const* d_in, const int* in_sizes, int n_in,
                              void* d_out, int out_size, void* d_ws, size_t ws_size,
                              hipStream_t stream) {
    const float* x      = (const float*)d_in[0];
    const float* W      = (const float*)d_in[1];
    const float* gamma  = (const float*)d_in[2];
    const float* beta   = (const float*)d_in[3];
    const int*   in_idx = (const int*)d_in[4];
    const int*   out_idx= (const int*)d_in[5];
    float* out   = (float*)d_out;
    char*  ws    = (char*)d_ws;
    float* stats = (float*)ws;
    float* ss    = stats + 128;

    hipMemsetAsync(d_ws, 0, 256 * sizeof(float), stream);

    if (ws_size >= WS_NEEDED) {
        unsigned short* Wf   = (unsigned short*)(ws + WF_OFF);
        unsigned short* outb = (unsigned short*)(ws + OUTB_OFF);

        hipMemsetAsync(outb, 0, ROWBUF_BYTES, stream);
        convert_w_kernel<<<(Kk * 4096 + 255) / 256, 256, 0, stream>>>(W, Wf);
        scatter_pk_kernel<<<Kk * BPK2, 256, 0, stream>>>(x, Wf, in_idx, out_idx, outb);
        bn_stats_bf16<<<1024, 256, 0, stream>>>(outb, stats);
        bn_finalize_kernel<<<1, 64, 0, stream>>>(stats, gamma, beta, ss);
        bn_apply_bf16<<<2048, 256, 0, stream>>>(outb, ss, out);
    } else {
        hipMemsetAsync(d_out, 0, (size_t)Nn * Cc * sizeof(float), stream);
        scatter_gemm_kernel<<<Kk * 1024, 256, 0, stream>>>(x, W, in_idx, out_idx, out);
        bn_stats_f32<<<1024, 256, 0, stream>>>(out, stats);
        bn_finalize_kernel<<<1, 64, 0, stream>>>(stats, gamma, beta, ss);
        bn_apply_f32<<<4096, 256, 0, stream>>>(out, ss);
    }
}